// Round 3
// baseline (134.035 us; speedup 1.0000x reference)
//
#include <hip/hip_runtime.h>
#include <math.h>

// Biquad highpass IIR over [B=128, C=2, T=65536] f32.
// R3: wave-autonomous single-wave blocks (BLK=64, 8 KiB private LDS),
// depth-2 double-buffered global prefetch (never drains vmcnt to 0),
// batched LDS phases (reads->regs, compute in regs, writes back).
// Numerics: chunks of L=64 + W=64 zero-state warm-up; pole radius 0.8234
// => boundary error ~4e-6, absmax floor 0.0156 is f32 contraction noise
// (proven R1/R2). LDS: 32-float rows, float4 slot rotated (slot=(g+row)&7)
// => all ds_*_b128, 8 lanes cover all 32 banks per phase.

#define T_LEN   65536
#define L_CHUNK 64
#define W_WARM  64
#define TS      32
#define BLK     64                        // one wave per block
#define NT      ((W_WARM + L_CHUNK) / TS) // 4 tiles; tiles 2..3 stored
#define CHUNK_SHIFT 10                    // log2(T_LEN / L_CHUNK)
#define ROWS    64                        // chunks per wave
#define WLDS    (ROWS * TS)               // 2048 floats = 8 KiB

__device__ __forceinline__ void lds_fence() {
    // lgkm-only: orders DS ops (in-order per wave => cross-lane visibility
    // within our single-wave block) without draining global-load vmcnt.
    asm volatile("s_waitcnt lgkmcnt(0)" ::: "memory");
}

__device__ __forceinline__ void load_tile(const float* __restrict__ x,
                                          int cg0, int cbase, int tile,
                                          float4* pf, int lane)
{
    #pragma unroll
    for (int p = 0; p < 8; ++p) {
        int q   = lane + (p << 6);
        int seg = q >> 3;
        int g   = q & 7;
        int pos = (cg0 + seg) * L_CHUNK - W_WARM + tile * TS + (g << 2);
        float4 v = make_float4(0.f, 0.f, 0.f, 0.f);
        if (pos >= cbase)                 // zero state before channel start
            v = *(const float4*)(x + pos);
        pf[p] = v;
    }
}

__global__ __launch_bounds__(BLK, 4)
void hp_biquad_kernel(const float* __restrict__ x, float* __restrict__ y,
                      float b0, float b1, float b2, float a1, float a2)
{
    __shared__ float wlds[WLDS];          // private to this block's one wave
    const int lane = threadIdx.x;
    const int cg0  = blockIdx.x * ROWS;
    // 1024 chunks per channel, 64 chunks per block => whole block is in one
    // channel; cbase is wave-uniform (scalarizes).
    const int cbase = (cg0 >> CHUNK_SHIFT) * T_LEN;

    float4 pf[2][8];
    load_tile(x, cg0, cbase, 0, pf[0], lane);   // depth-2 pipeline prologue
    load_tile(x, cg0, cbase, 1, pf[1], lane);

    float x1 = 0.f, x2 = 0.f, y1 = 0.f, y2 = 0.f;

    #pragma unroll
    for (int tile = 0; tile < NT; ++tile) {
        float4* cur = pf[tile & 1];

        // ---- regs -> LDS, seg-major swizzled, b128 ----
        #pragma unroll
        for (int p = 0; p < 8; ++p) {
            int q    = lane + (p << 6);
            int seg  = q >> 3;
            int g    = q & 7;
            int slot = ((g + seg) & 7) << 2;
            *(float4*)&wlds[seg * TS + slot] = cur[p];
        }
        lds_fence();

        // refill the just-freed buffer with tile+2 (window = 2 tiles)
        if (tile + 2 < NT)
            load_tile(x, cg0, cbase, tile + 2, cur, lane);

        // ---- my row -> registers (8 independent ds_read_b128) ----
        float4 r[8];
        #pragma unroll
        for (int g = 0; g < 8; ++g) {
            int slot = ((g + lane) & 7) << 2;
            r[g] = *(float4*)&wlds[lane * TS + slot];
        }

        // ---- serial biquad over 32 samples, entirely in registers ----
        #pragma unroll
        for (int g = 0; g < 8; ++g) {
            float4 v = r[g];
            float yv;
            yv = b0 * v.x + b1 * x1 + b2 * x2 - a1 * y1 - a2 * y2;
            x2 = x1; x1 = v.x; y2 = y1; y1 = yv; v.x = yv;
            yv = b0 * v.y + b1 * x1 + b2 * x2 - a1 * y1 - a2 * y2;
            x2 = x1; x1 = v.y; y2 = y1; y1 = yv; v.y = yv;
            yv = b0 * v.z + b1 * x1 + b2 * x2 - a1 * y1 - a2 * y2;
            x2 = x1; x1 = v.z; y2 = y1; y1 = yv; v.z = yv;
            yv = b0 * v.w + b1 * x1 + b2 * x2 - a1 * y1 - a2 * y2;
            x2 = x1; x1 = v.w; y2 = y1; y1 = yv; v.w = yv;
            r[g] = v;
        }

        // ---- data tiles: transpose back through LDS, coalesced store ----
        if (tile >= W_WARM / TS) {
            #pragma unroll
            for (int g = 0; g < 8; ++g) {
                int slot = ((g + lane) & 7) << 2;
                *(float4*)&wlds[lane * TS + slot] = r[g];
            }
            lds_fence();
            #pragma unroll
            for (int p = 0; p < 8; ++p) {
                int q    = lane + (p << 6);
                int seg  = q >> 3;
                int g    = q & 7;
                int slot = ((g + seg) & 7) << 2;
                float4 v = *(float4*)&wlds[seg * TS + slot];
                int pos  = (cg0 + seg) * L_CHUNK - W_WARM + tile * TS + (g << 2);
                *(float4*)(y + pos) = v;
            }
        }
        lds_fence();   // keep compiler from sliding next tile's writes up
    }
}

extern "C" void kernel_launch(void* const* d_in, const int* in_sizes, int n_in,
                              void* d_out, int out_size, void* d_ws, size_t ws_size,
                              hipStream_t stream)
{
    const float* x = (const float*)d_in[0];
    float* y = (float*)d_out;

    // Same double-precision coefficient math as the reference, cast to f32.
    const double SR = 16000.0, FLO = 200.0, FHI = 1200.0;
    const double freq   = 0.5 * (FLO + FHI);      // 700 Hz
    const double cutoff = freq / SR;
    const double q      = 0.70710678;
    const double w0 = 2.0 * M_PI * cutoff;
    const double cw = cos(w0), sw = sin(w0);
    const double alpha = sw / (2.0 * q);
    const double b0 = (1.0 + cw) / 2.0;
    const double b1 = -(1.0 + cw);
    const double b2 = (1.0 + cw) / 2.0;
    const double a0 = 1.0 + alpha;
    const double a1 = -2.0 * cw;
    const double a2 = 1.0 - alpha;
    const float fb0 = (float)(b0 / a0), fb1 = (float)(b1 / a0), fb2 = (float)(b2 / a0);
    const float fa1 = (float)(a1 / a0), fa2 = (float)(a2 / a0);

    const int total  = 128 * 2 * T_LEN;            // 16,777,216 samples
    const int chunks = total / L_CHUNK;            // 262,144
    const int blocks = chunks / BLK;               // 4096 single-wave blocks

    hp_biquad_kernel<<<blocks, BLK, 0, stream>>>(x, y, fb0, fb1, fb2, fa1, fa2);
    (void)in_sizes; (void)n_in; (void)out_size; (void)d_ws; (void)ws_size;
}

// Round 4
// 115.362 us; speedup vs baseline: 1.1619x; 1.1619x over previous
//
#include <hip/hip_runtime.h>
#include <math.h>

// Biquad highpass IIR over [B=128, C=2, T=65536] f32.
// R4: async global->LDS DMA (global_load_lds_dwordx4) into 2x8KiB buffers,
// hand-placed partial vmcnt waits (cp.async-style). DMA lane->LDS layout is
// fixed (base + lane*16), so we permute WHICH global float4 each lane fetches
// (slot q = row*8 + ((j+row)&7)) making compute-phase row reads conflict-free
// ds_read_b128 with zero copy phases. Outputs written in-place into the
// consumed staging buffers; ONE final store phase writes each chunk's full
// 256B sector contiguously (1 KiB linear per instruction) -- fixes R3's
// 1.55x write amplification (half-sector writes evicted between tiles).
// Numerics: L=64-sample chunks + W=64 zero-state warm-up (pole radius
// 0.8234 => boundary error ~4e-6; absmax floor 0.0156 = f32 contraction
// noise, proven R1-R3).

#define T_LEN    65536
#define L_CHUNK  64
#define W_WARM   64
#define TS       32
#define BLK      64                  // one wave per block
#define ROWS     64                  // chunks per wave
#define BUF_F    (ROWS * TS)         // 2048 floats = 8 KiB per buffer
#define BLOCKS_PER_CH 16             // (T_LEN/L_CHUNK)/ROWS

#define WAITVM(n) asm volatile("s_waitcnt vmcnt(" #n ")" ::: "memory")

__device__ __forceinline__ void lds_fence() {
    // orders DS ops (in-order per wave; block = one wave) without draining vmcnt
    asm volatile("s_waitcnt lgkmcnt(0)" ::: "memory");
}

// DMA one 8 KiB tile into LDS. Instr i writes lane k's 16B to buf+i*1024+k*16.
// Global source permuted so LDS slot q=i*64+lane holds row l=q>>3's float4
// #j where j=((q&7)-l)&7  (=> compute reads at slot l*8+((g+l)&7) are
// bank-conflict-free).
__device__ __forceinline__ void dma_tile(const float* __restrict__ x,
                                         int base_f, int tile, float* buf)
{
    #pragma unroll
    for (int i = 0; i < 8; ++i) {
        int pos = base_f + i * 512 + tile * TS;
        pos = pos < 0 ? 0 : pos;     // block 0 pre-channel clamp (values zeroed later)
        __builtin_amdgcn_global_load_lds(
            (__attribute__((address_space(1))) void*)(void*)(x + pos),
            (__attribute__((address_space(3))) void*)(buf + i * 256),
            16, 0, 0);
    }
}

template <bool WARM>
__device__ __forceinline__ void tile_filter(float* buf, int lane, bool ch0,
    float c_b0, float c_b1, float c_b2, float c_a1, float c_a2,
    float& x1, float& x2, float& y1, float& y2)
{
    float4 r[8];
    #pragma unroll
    for (int g = 0; g < 8; ++g)
        r[g] = *(float4*)&buf[(lane * 8 + ((g + lane) & 7)) * 4];

    if (WARM && ch0) {   // channel-start row: pre-channel reads are garbage => state 0
        #pragma unroll
        for (int g = 0; g < 8; ++g) r[g] = make_float4(0.f, 0.f, 0.f, 0.f);
    }

    #pragma unroll
    for (int g = 0; g < 8; ++g) {
        float4 v = r[g];
        float yv;
        yv = c_b0*v.x + c_b1*x1 + c_b2*x2 - c_a1*y1 - c_a2*y2;
        x2 = x1; x1 = v.x; y2 = y1; y1 = yv; v.x = yv;
        yv = c_b0*v.y + c_b1*x1 + c_b2*x2 - c_a1*y1 - c_a2*y2;
        x2 = x1; x1 = v.y; y2 = y1; y1 = yv; v.y = yv;
        yv = c_b0*v.z + c_b1*x1 + c_b2*x2 - c_a1*y1 - c_a2*y2;
        x2 = x1; x1 = v.z; y2 = y1; y1 = yv; v.z = yv;
        yv = c_b0*v.w + c_b1*x1 + c_b2*x2 - c_a1*y1 - c_a2*y2;
        x2 = x1; x1 = v.w; y2 = y1; y1 = yv; v.w = yv;
        if (!WARM) r[g] = v;
    }

    if (!WARM) {         // in-place: staging buffer becomes output buffer
        #pragma unroll
        for (int g = 0; g < 8; ++g)
            *(float4*)&buf[(lane * 8 + ((g + lane) & 7)) * 4] = r[g];
    }
}

__global__ __launch_bounds__(BLK, 4)
void hp_biquad_kernel(const float* __restrict__ x, float* __restrict__ y,
                      float c_b0, float c_b1, float c_b2, float c_a1, float c_a2)
{
    __shared__ float bufA[BUF_F];
    __shared__ float bufB[BUF_F];
    const int lane = threadIdx.x;
    const int cg0  = blockIdx.x * ROWS;
    const bool ch0 = ((blockIdx.x & (BLOCKS_PER_CH - 1)) == 0) && (lane == 0);

    // per-lane DMA source base (floats): row l0 = lane>>3, permuted j0
    const int l0  = lane >> 3;
    const int j0  = ((lane & 7) - l0) & 7;
    const int bsf = (cg0 + l0) * L_CHUNK - W_WARM + j0 * 4;

    float x1 = 0.f, x2 = 0.f, y1 = 0.f, y2 = 0.f;

    // ---- cp.async-style pipeline over 4 tiles, 2 buffers ----
    dma_tile(x, bsf, 0, bufA);                 // out: 8
    dma_tile(x, bsf, 1, bufB);                 // out: 16

    WAITVM(8);                                  // t0 landed
    tile_filter<true>(bufA, lane, ch0, c_b0, c_b1, c_b2, c_a1, c_a2, x1, x2, y1, y2);
    lds_fence();                                // A's reads retired before refill
    dma_tile(x, bsf, 2, bufA);                 // out: <=8(t1) + 8

    WAITVM(8);                                  // t1 landed
    tile_filter<true>(bufB, lane, ch0, c_b0, c_b1, c_b2, c_a1, c_a2, x1, x2, y1, y2);
    lds_fence();
    dma_tile(x, bsf, 3, bufB);                 // out: <=8(t2) + 8

    WAITVM(8);                                  // t2 landed
    tile_filter<false>(bufA, lane, ch0, c_b0, c_b1, c_b2, c_a1, c_a2, x1, x2, y1, y2);

    WAITVM(0);                                  // t3 landed
    tile_filter<false>(bufB, lane, ch0, c_b0, c_b1, c_b2, c_a1, c_a2, x1, x2, y1, y2);
    lds_fence();                                // in-place writes ordered before store reads

    // ---- combined store: pos = cg0*64 + q*4 -> perfectly linear stream,
    // each chunk's 256B sector written whole; 1 KiB contiguous per instr ----
    const int ybase = cg0 * L_CHUNK + lane * 4;
    #pragma unroll
    for (int p = 0; p < 16; ++p) {
        int q   = lane + p * 64;
        int seg = q >> 4;                       // chunk row 0..63
        int jj  = q & 15;                       // float4 index within chunk
        float* b = (jj < 8) ? bufA : bufB;      // first half = tile2, second = tile3
        int g   = jj & 7;
        float4 v = *(float4*)&b[(seg * 8 + ((g + seg) & 7)) * 4];
        *(float4*)(y + ybase + p * 256) = v;
    }
}

extern "C" void kernel_launch(void* const* d_in, const int* in_sizes, int n_in,
                              void* d_out, int out_size, void* d_ws, size_t ws_size,
                              hipStream_t stream)
{
    const float* x = (const float*)d_in[0];
    float* y = (float*)d_out;

    // Same double-precision coefficient math as the reference, cast to f32.
    const double SR = 16000.0, FLO = 200.0, FHI = 1200.0;
    const double freq   = 0.5 * (FLO + FHI);      // 700 Hz
    const double cutoff = freq / SR;
    const double q      = 0.70710678;
    const double w0 = 2.0 * M_PI * cutoff;
    const double cw = cos(w0), sw = sin(w0);
    const double alpha = sw / (2.0 * q);
    const double b0 = (1.0 + cw) / 2.0;
    const double b1 = -(1.0 + cw);
    const double b2 = (1.0 + cw) / 2.0;
    const double a0 = 1.0 + alpha;
    const double a1 = -2.0 * cw;
    const double a2 = 1.0 - alpha;
    const float fb0 = (float)(b0 / a0), fb1 = (float)(b1 / a0), fb2 = (float)(b2 / a0);
    const float fa1 = (float)(a1 / a0), fa2 = (float)(a2 / a0);

    const int total  = 128 * 2 * T_LEN;            // 16,777,216 samples
    const int chunks = total / L_CHUNK;            // 262,144
    const int blocks = chunks / ROWS;              // 4096 single-wave blocks

    hp_biquad_kernel<<<blocks, BLK, 0, stream>>>(x, y, fb0, fb1, fb2, fa1, fa2);
    (void)in_sizes; (void)n_in; (void)out_size; (void)d_ws; (void)ws_size;
}